// Round 7
// baseline (575.622 us; speedup 1.0000x reference)
//
#include <hip/hip_runtime.h>
#include <math.h>

// ---------------------------------------------------------------------------
// MoE top-2/8, H=768, I=1536, T=2048. bf16 MFMA 16x16x32, fp32 accum.
// R7: ONE persistent kernel, 256 blocks x 256 thr (__launch_bounds__(256,1)
// => co-resident by construction on 256 CUs), software grid barrier
// (device-scope atomics + generation counter; barrier state zeroed by a tiny
// init dispatch). R6's hipLaunchCooperativeKernel silently failed to launch
// (output = memset zeros); this removes the cooperative API dependency.
// Phase bodies verbatim from the PASSING R5 kernels (packed swizzled 16KB
// tiles, global_load_lds width-16, 128x128 blocks, 64x64/wave).
// Phases: init+router+wpack | prefix | scatter | apack | gemm1 | gemm2 | combine
// ---------------------------------------------------------------------------

typedef unsigned short u16;
typedef __attribute__((ext_vector_type(8))) short bhalf8;   // 8 bf16
typedef __attribute__((ext_vector_type(4))) float floatx4;  // MFMA C/D

#define HD 768
#define ID 1536
#define NE 8
#define TT 2048
#define SLOTS 5120   // 4096 assignments + per-expert pad to 128
#define NBLK 256

__device__ __forceinline__ float b2f(u16 u) {
    union { unsigned int i; float f; } v; v.i = ((unsigned int)u) << 16; return v.f;
}
__device__ __forceinline__ u16 f2b(float f) {
    union { float f; unsigned int i; } v; v.f = f;
    unsigned int i = v.i;
    return (u16)((i + 0x7FFFu + ((i >> 16) & 1u)) >> 16);  // RNE
}
// async global->LDS, 16B/lane; LDS dest = wave-uniform base + lane*16
__device__ __forceinline__ void glds16(const u16* g, u16* l) {
    __builtin_amdgcn_global_load_lds(
        (const __attribute__((address_space(1))) unsigned int*)g,
        (__attribute__((address_space(3))) unsigned int*)l, 16, 0, 0);
}

// grid barrier: all NBLK blocks co-resident (grid <= 1 block/CU * 256 CU).
// Device-scope atomics + threadfence for cross-XCD visibility (G16).
__device__ __forceinline__ void gbar(int* cnt, int* gen) {
    __syncthreads();
    if (threadIdx.x == 0) {
        __threadfence();  // make this block's writes agent-visible
        int g = __hip_atomic_load(gen, __ATOMIC_RELAXED, __HIP_MEMORY_SCOPE_AGENT);
        int a = __hip_atomic_fetch_add(cnt, 1, __ATOMIC_ACQ_REL, __HIP_MEMORY_SCOPE_AGENT);
        if (a == NBLK - 1) {
            __hip_atomic_store(cnt, 0, __ATOMIC_RELAXED, __HIP_MEMORY_SCOPE_AGENT);
            __hip_atomic_store(gen, g + 1, __ATOMIC_RELEASE, __HIP_MEMORY_SCOPE_AGENT);
        } else {
            while (__hip_atomic_load(gen, __ATOMIC_ACQUIRE, __HIP_MEMORY_SCOPE_AGENT) == g)
                __builtin_amdgcn_s_sleep(8);
        }
        __threadfence();  // see other blocks' writes
    }
    __syncthreads();
}

// zero barrier state + header before the persistent kernel
__global__ void init_k(char* ws) {
    if (threadIdx.x < 64) ((int*)ws)[threadIdx.x] = 0;  // bytes 0..256
}

// pack one 64k x 128n weight sub-tile into two swizzled 16KB tiles' halves
__device__ __forceinline__ void wpack_body(
        const void* __restrict__ src, u16* __restrict__ dst, int K, int N,
        int ktiles, int ntiles, int e, int kt, int nt, int bf, u16* t, int tid) {
    int kr = tid >> 2, ng = (tid & 3) * 32;  // k-row, 32 n's
    size_t srow = ((size_t)e * K + (size_t)kt * 64 + kr) * N + (size_t)nt * 128 + ng;
    union { uint4 v[4]; u16 u[32]; } buf;
    if (bf) {
        const u16* s = (const u16*)src + srow;
#pragma unroll
        for (int c = 0; c < 4; ++c) buf.v[c] = *(const uint4*)&s[c * 8];
    } else {
        const float* s = (const float*)src + srow;
#pragma unroll
        for (int c = 0; c < 8; ++c) {
            float4 f = *(const float4*)&s[c * 4];
            buf.u[c * 4 + 0] = f2b(f.x); buf.u[c * 4 + 1] = f2b(f.y);
            buf.u[c * 4 + 2] = f2b(f.z); buf.u[c * 4 + 3] = f2b(f.w);
        }
    }
#pragma unroll
    for (int jj = 0; jj < 32; ++jj) {
        int n = ng + jj;
        t[n * 64 + (((kr >> 3) ^ (n & 7)) << 3) + (kr & 7)] = buf.u[jj];
    }
    __syncthreads();
    u16* d = dst + ((((size_t)e * ntiles + nt) * ktiles + kt) << 13);
#pragma unroll
    for (int i = 0; i < 4; ++i) {
        int off = tid * 8 + i * 2048;
        *(uint4*)(d + off) = *(const uint4*)&t[off];
    }
}

__global__ __launch_bounds__(256, 1) void moe_mega(
        const void* __restrict__ x, const void* __restrict__ rw,
        const void* __restrict__ wg, const void* __restrict__ wu,
        const void* __restrict__ wd, void* __restrict__ out,
        char* __restrict__ ws) {
    __shared__ u16 smem[24576];  // 48 KB, aliased by every phase
    const int bid = blockIdx.x, tid = threadIdx.x;
    const int lane = tid & 63, wave = tid >> 6;

    int*   cursorp = (int*)(ws + 32);
    int*   basep   = (int*)(ws + 64);
    int*   totalp  = (int*)(ws + 96);
    int*   bcnt    = (int*)(ws + 128);
    int*   bgen    = (int*)(ws + 160);
    int*   topki   = (int*)(ws + 256);         // [4096]
    float* topkp   = (float*)(ws + 16640);     // [4096]
    int*   tokof   = (int*)(ws + 33024);       // [5120]
    float* pslotp  = (float*)(ws + 53504);     // [5120]
    int*   slotmap = (int*)(ws + 73984);       // [4096]
    float* blockpart = (float*)(ws + 90368);   // [512*8]
    u16*   apack   = (u16*)(ws + 106752);      // 40*12 tiles * 16 KB
    u16*   actp    = (u16*)(ws + 7971072);     // 40*24 tiles
    u16*   wgp     = (u16*)(ws + 23699712);    // 8*12*12 tiles
    u16*   wup     = (u16*)(ws + 42574080);
    u16*   wdp     = (u16*)(ws + 61448448);    // 8*6*24 tiles -> 80,322,816
    float* ybuf    = (float*)(ws + 23699712);  // overlays wgp: phase-ordered safe

    // ---- dtype sniff (uniform in every block) ----
    int bf;
    {
        if (tid < 64) {
            int c = 0;
#pragma unroll
            for (int j = 0; j < 4; ++j) {
                u16 w = ((const u16*)x)[tid + 64 * j];
                int ex = (w >> 7) & 0xFF;
                c += (ex >= 118 && ex <= 135);  // bf16 ~255/256 hit, fp32 ~136
            }
#pragma unroll
            for (int off = 32; off > 0; off >>= 1) c += __shfl_xor(c, off);
            if (tid == 0) *(int*)smem = (c >= 200) ? 1 : 0;
        }
        __syncthreads();
        bf = *(int*)smem;
        __syncthreads();
    }

    // ===== phase 0: init slices + router (2 reps) + weight packing =====
    for (int i = bid * 256 + tid; i < SLOTS; i += NBLK * 256) {
        tokof[i] = -1; pslotp[i] = 0.f;
    }
    for (int rep = 0; rep < 2; ++rep) {
        float* sp = (float*)smem;  // [4][8]
        int t = (rep * NBLK + bid) * 4 + wave;
        const float* xf = (const float*)x + (size_t)t * HD;
        const u16*   xh = (const u16*)x + (size_t)t * HD;
        const float* rf = (const float*)rw;
        const u16*   rh = (const u16*)rw;
        float acc[NE];
#pragma unroll
        for (int e = 0; e < NE; ++e) acc[e] = 0.f;
        for (int j = 0; j < HD / 64; ++j) {
            int h = lane + 64 * j;
            float xv = bf ? b2f(xh[h]) : xf[h];
#pragma unroll
            for (int e = 0; e < NE; ++e)
                acc[e] += xv * (bf ? b2f(rh[h * NE + e]) : rf[h * NE + e]);
        }
#pragma unroll
        for (int e = 0; e < NE; ++e) {
            float v = acc[e];
#pragma unroll
            for (int off = 32; off > 0; off >>= 1) v += __shfl_xor(v, off);
            acc[e] = v;
        }
        if (lane == 0) {
            float m = acc[0];
            for (int e = 1; e < NE; ++e) m = fmaxf(m, acc[e]);
            float p[NE], s = 0.f;
            for (int e = 0; e < NE; ++e) { p[e] = expf(acc[e] - m); s += p[e]; }
            float inv = 1.f / s;
            for (int e = 0; e < NE; ++e) { p[e] *= inv; sp[wave * NE + e] = p[e]; }
            int i1 = 0; float p1 = p[0];
            for (int e = 1; e < NE; ++e) if (p[e] > p1) { p1 = p[e]; i1 = e; }  // first-max
            int i2 = -1; float p2 = -1.f;
            for (int e = 0; e < NE; ++e) if (e != i1 && p[e] > p2) { p2 = p[e]; i2 = e; }
            if (i2 < 0) { i2 = (i1 + 1) & 7; p2 = p[i2]; }  // NaN guard
            float sn = 1.f / (p1 + p2);
            topki[2 * t] = i1;  topki[2 * t + 1] = i2;
            topkp[2 * t] = p1 * sn;  topkp[2 * t + 1] = p2 * sn;
        }
        __syncthreads();
        if (tid < NE)
            blockpart[(rep * NBLK + bid) * NE + tid] =
                sp[tid] + sp[NE + tid] + sp[2 * NE + tid] + sp[3 * NE + tid];
        __syncthreads();
    }
    for (int T = bid; T < 3456; T += NBLK) {  // 2304 wg/wu + 1152 wd tasks
        const void* src; u16* dst; int K, N, ktiles, ntiles, e, kt, nt;
        if (T < 2304) {
            int z = T / 144, rem = T - z * 144;
            nt = rem / 12; kt = rem - nt * 12;
            e = z & 7;
            src = (z < NE) ? wg : wu;
            dst = (z < NE) ? wgp : wup;
            K = HD; N = ID; ktiles = 12; ntiles = 12;
        } else {
            int T2 = T - 2304;
            e = T2 / 144; int rem = T2 - e * 144;
            nt = rem / 24; kt = rem - nt * 24;
            src = wd; dst = wdp; K = ID; N = HD; ktiles = 24; ntiles = 6;
        }
        wpack_body(src, dst, K, N, ktiles, ntiles, e, kt, nt, bf, smem, tid);
        __syncthreads();
    }
    gbar(bcnt, bgen);

    // ===== phase 1: prefix (block 0) =====
    if (bid == 0) {
        int* hist = (int*)smem;
        float* psum = (float*)((char*)smem + 64);
        if (tid < NE) { hist[tid] = 0; psum[tid] = 0.f; }
        __syncthreads();
        for (int i = tid; i < TT * 2; i += 256) atomicAdd(&hist[topki[i] & 7], 1);
        for (int i = tid; i < 512 * NE; i += 256) atomicAdd(&psum[i & 7], blockpart[i]);
        __syncthreads();
        if (tid == 0) {
            int cum = 0; float aux = 0.f;
            for (int e = 0; e < NE; ++e) {
                int c = hist[e];
                basep[e] = cum; cum += (c + 127) & ~127;
                cursorp[e] = 0;
                aux += ((float)c / (float)(TT * 2)) * (psum[e] / (float)TT);
            }
            *totalp = cum;
            float auxv = aux * (float)NE * 0.01f;
            if (bf) ((u16*)out)[(size_t)TT * HD] = f2b(auxv);
            else    ((float*)out)[(size_t)TT * HD] = auxv;
        }
    }
    gbar(bcnt, bgen);

    // ===== phase 2: scatter (blocks 0..7) =====
    if (bid < 8) {
        int* lcnt = (int*)smem;
        int* lbase = (int*)((char*)smem + 64);
        if (tid < NE) lcnt[tid] = 0;
        __syncthreads();
        int t = bid * 256 + tid;
        int e0 = topki[2 * t] & 7, e1 = topki[2 * t + 1] & 7;
        float q0 = topkp[2 * t], q1 = topkp[2 * t + 1];
        int l0 = atomicAdd(&lcnt[e0], 1);
        int l1 = atomicAdd(&lcnt[e1], 1);
        __syncthreads();
        if (tid < NE) lbase[tid] = atomicAdd(&cursorp[tid], lcnt[tid]);
        __syncthreads();
        int s0 = min(max(basep[e0] + lbase[e0] + l0, 0), SLOTS - 1);
        int s1 = min(max(basep[e1] + lbase[e1] + l1, 0), SLOTS - 1);
        tokof[s0] = t;  pslotp[s0] = q0;  slotmap[2 * t] = s0;
        tokof[s1] = t;  pslotp[s1] = q1;  slotmap[2 * t + 1] = s1;
    }
    gbar(bcnt, bgen);

    // ===== phase 3: apack (gather tokens -> packed swizzled A tiles) =====
    {
        int total = *totalp;
        for (int T = bid; T < 480; T += NBLK) {
            int mt = T / 12, kt = T - mt * 12;
            if (mt * 128 >= total) continue;
            int ml = tid >> 1, half = tid & 1;
            int tok = tokof[mt * 128 + ml];
            union { uint4 v[4]; u16 u[32]; } buf;
            if ((unsigned)tok < (unsigned)TT) {
                if (bf) {
                    const u16* s = (const u16*)x + (size_t)tok * HD + kt * 64 + half * 32;
#pragma unroll
                    for (int c = 0; c < 4; ++c) buf.v[c] = *(const uint4*)&s[c * 8];
                } else {
                    const float* s = (const float*)x + (size_t)tok * HD + kt * 64 + half * 32;
#pragma unroll
                    for (int c = 0; c < 8; ++c) {
                        float4 f = *(const float4*)&s[c * 4];
                        buf.u[c * 4 + 0] = f2b(f.x); buf.u[c * 4 + 1] = f2b(f.y);
                        buf.u[c * 4 + 2] = f2b(f.z); buf.u[c * 4 + 3] = f2b(f.w);
                    }
                }
            } else {
#pragma unroll
                for (int c = 0; c < 4; ++c) buf.v[c] = make_uint4(0, 0, 0, 0);
            }
            u16* dst = apack + (((size_t)mt * 12 + kt) << 13) + ml * 64;
#pragma unroll
            for (int c = 0; c < 4; ++c) {
                int pc = (half * 4 + c) ^ (ml & 7);
                *(uint4*)(dst + pc * 8) = buf.v[c];
            }
        }
    }
    gbar(bcnt, bgen);

    // ===== phase 4: gemm1  act = silu(A Wg) * (A Wu) =====
    {
        int total = *totalp;
        for (int T = bid; T < 480; T += NBLK) {
            int mt = T / 12, nt = T - mt * 12;
            if (mt * 128 >= total) continue;
            u16* As = smem; u16* Bg = smem + 8192; u16* Bu = smem + 16384;
            int e = 7;
            while (e > 0 && mt * 128 < basep[e]) --e;
            int wm = (wave & 1) * 64, wn = (wave >> 1) * 64;
            int llo = lane & 15, lq = lane >> 4;
            const u16* atile = apack + (((size_t)mt * 12) << 13);
            const u16* gtile = wgp + ((((size_t)e * 12 + nt) * 12) << 13);
            const u16* utile = wup + ((((size_t)e * 12 + nt) * 12) << 13);
            floatx4 accG[4][4], accU[4][4];
#pragma unroll
            for (int i = 0; i < 4; ++i)
#pragma unroll
                for (int j = 0; j < 4; ++j) {
                    accG[i][j] = floatx4{0.f, 0.f, 0.f, 0.f};
                    accU[i][j] = floatx4{0.f, 0.f, 0.f, 0.f};
                }
            for (int kt = 0; kt < 12; ++kt) {
                const u16* ga = atile + (kt << 13);
                const u16* gg = gtile + (kt << 13);
                const u16* gu = utile + (kt << 13);
                __syncthreads();
#pragma unroll
                for (int i = 0; i < 4; ++i) {
                    int off = tid * 8 + i * 2048;
                    glds16(ga + off, As + off);
                    glds16(gg + off, Bg + off);
                    glds16(gu + off, Bu + off);
                }
                asm volatile("s_waitcnt vmcnt(0)" ::: "memory");
                __syncthreads();
#pragma unroll
                for (int kk = 0; kk < 2; ++kk) {
                    int q = kk * 4 + lq;
                    bhalf8 af[4], bg[4], bu[4];
#pragma unroll
                    for (int i = 0; i < 4; ++i) {
                        int m = wm + i * 16 + llo;
                        af[i] = *(const bhalf8*)&As[m * 64 + ((q ^ (m & 7)) << 3)];
                        int n = wn + i * 16 + llo;
                        bg[i] = *(const bhalf8*)&Bg[n * 64 + ((q ^ (n & 7)) << 3)];
                        bu[i] = *(const bhalf8*)&Bu[n * 64 + ((q ^ (n & 7)) << 3)];
                    }
#pragma unroll
                    for (int i = 0; i < 4; ++i)
#pragma unroll
                        for (int j = 0; j < 4; ++j) {
                            accG[i][j] = __builtin_amdgcn_mfma_f32_16x16x32_bf16(af[i], bg[j], accG[i][j], 0, 0, 0);
                            accU[i][j] = __builtin_amdgcn_mfma_f32_16x16x32_bf16(af[i], bu[j], accU[i][j], 0, 0, 0);
                        }
                }
            }
            __syncthreads();
            u16* Ah = smem;  // 32 KB
            int q4 = lq * 4;
#pragma unroll
            for (int i = 0; i < 4; ++i)
#pragma unroll
                for (int j = 0; j < 4; ++j)
#pragma unroll
                    for (int rr = 0; rr < 4; ++rr) {
                        int m = wm + i * 16 + q4 + rr;
                        int n = wn + j * 16 + llo;
                        float g = accG[i][j][rr], u = accU[i][j][rr];
                        Ah[m * 128 + n] = f2b((g / (1.f + expf(-g))) * u);
                    }
            __syncthreads();
            u16* dst = actp + (((size_t)mt * 24 + nt * 2) << 13);
#pragma unroll
            for (int s = 0; s < 2; ++s)
#pragma unroll
                for (int i = 0; i < 4; ++i) {
                    int off = tid * 8 + i * 2048;
                    int m = off >> 6;
                    int pc = (off >> 3) & 7;
                    int q = pc ^ (m & 7);
                    *(uint4*)(dst + ((size_t)s << 13) + off) =
                        *(const uint4*)&Ah[m * 128 + s * 64 + q * 8];
                }
            __syncthreads();
        }
    }
    gbar(bcnt, bgen);

    // ===== phase 5: gemm2  y = pslot * (act Wd) =====
    {
        int total = *totalp;
        for (int T = bid; T < 240; T += NBLK) {
            int mt = T / 6, nt = T - mt * 6;
            if (mt * 128 >= total) continue;
            u16* As = smem; u16* Bs = smem + 8192;
            int e = 7;
            while (e > 0 && mt * 128 < basep[e]) --e;
            int wm = (wave & 1) * 64, wn = (wave >> 1) * 64;
            int llo = lane & 15, lq = lane >> 4;
            const u16* atile = actp + (((size_t)mt * 24) << 13);
            const u16* btile = wdp + ((((size_t)e * 6 + nt) * 24) << 13);
            floatx4 acc[4][4];
#pragma unroll
            for (int i = 0; i < 4; ++i)
#pragma unroll
                for (int j = 0; j < 4; ++j) acc[i][j] = floatx4{0.f, 0.f, 0.f, 0.f};
            for (int kt = 0; kt < 24; ++kt) {
                const u16* ga = atile + (kt << 13);
                const u16* gb = btile + (kt << 13);
                __syncthreads();
#pragma unroll
                for (int i = 0; i < 4; ++i) {
                    int off = tid * 8 + i * 2048;
                    glds16(ga + off, As + off);
                    glds16(gb + off, Bs + off);
                }
                asm volatile("s_waitcnt vmcnt(0)" ::: "memory");
                __syncthreads();
#pragma unroll
                for (int kk = 0; kk < 2; ++kk) {
                    int q = kk * 4 + lq;
                    bhalf8 af[4], bfr[4];
#pragma unroll
                    for (int i = 0; i < 4; ++i) {
                        int m = wm + i * 16 + llo;
                        af[i] = *(const bhalf8*)&As[m * 64 + ((q ^ (m & 7)) << 3)];
                        int n = wn + i * 16 + llo;
                        bfr[i] = *(const bhalf8*)&Bs[n * 64 + ((q ^ (n & 7)) << 3)];
                    }
#pragma unroll
                    for (int i = 0; i < 4; ++i)
#pragma unroll
                        for (int j = 0; j < 4; ++j)
                            acc[i][j] = __builtin_amdgcn_mfma_f32_16x16x32_bf16(af[i], bfr[j], acc[i][j], 0, 0, 0);
                }
            }
            int q4 = lq * 4;
#pragma unroll
            for (int i = 0; i < 4; ++i)
#pragma unroll
                for (int rr = 0; rr < 4; ++rr) {
                    int m = mt * 128 + wm + i * 16 + q4 + rr;
                    float p = pslotp[m];
#pragma unroll
                    for (int j = 0; j < 4; ++j) {
                        int n = nt * 128 + wn + j * 16 + llo;
                        ybuf[(size_t)m * HD + n] = p * acc[i][j][rr];
                    }
                }
            __syncthreads();
        }
    }
    gbar(bcnt, bgen);

    // ===== phase 6: combine =====
#pragma unroll
    for (int r = 0; r < 6; ++r) {
        int g = (r * NBLK + bid) * 256 + tid;  // TT*192 quads total
        int t = g / 192;
        int q = (g - t * 192) * 4;
        int s0 = min(max(slotmap[2 * t], 0), SLOTS - 1);
        int s1 = min(max(slotmap[2 * t + 1], 0), SLOTS - 1);
        float4 a = *(const float4*)&ybuf[(size_t)s0 * HD + q];
        float4 b = *(const float4*)&ybuf[(size_t)s1 * HD + q];
        float4 rv;
        rv.x = a.x + b.x; rv.y = a.y + b.y; rv.z = a.z + b.z; rv.w = a.w + b.w;
        if (bf) {
            ushort4 o;
            o.x = f2b(rv.x); o.y = f2b(rv.y); o.z = f2b(rv.z); o.w = f2b(rv.w);
            *(ushort4*)((u16*)out + (size_t)t * HD + q) = o;
        } else {
            *(float4*)((float*)out + (size_t)t * HD + q) = rv;
        }
    }
}

extern "C" void kernel_launch(void* const* d_in, const int* in_sizes, int n_in,
                              void* d_out, int out_size, void* d_ws, size_t ws_size,
                              hipStream_t stream) {
    if (ws_size < 80322816u) return;  // clean absmax-fail beats a wild write
    const void* x  = d_in[0];
    const void* rw = d_in[1];
    const void* wg = d_in[2];
    const void* wu = d_in[3];
    const void* wd = d_in[4];
    char* ws = (char*)d_ws;
    init_k<<<1, 64, 0, stream>>>(ws);
    moe_mega<<<NBLK, 256, 0, stream>>>(x, rw, wg, wu, wd, d_out, ws);
}

// Round 8
// 246.353 us; speedup vs baseline: 2.3366x; 2.3366x over previous
//
#include <hip/hip_runtime.h>
#include <math.h>

// ---------------------------------------------------------------------------
// MoE top-2/8, H=768, I=1536, T=2048. bf16 MFMA 16x16x32, fp32 accum.
// R8: back to stream-ordered multi-kernel (R7 persistent kernel + software
// grid barrier caused L2-invalidate storms: 2.4% MfmaUtil, 217MB refetch,
// 533us). R5 bodies, 6 dispatches (was 10):
//   setup(init+router+wpack x3) -> sortscat(prefix+scatter, atomic-free) ->
//   apack -> gemm1 -> gemm2 -> combine
// Packed swizzled 16KB tiles (pc = q ^ (row&7)), global_load_lds width-16,
// 128x128 blocks, 64x64/wave.
// ---------------------------------------------------------------------------

typedef unsigned short u16;
typedef __attribute__((ext_vector_type(8))) short bhalf8;   // 8 bf16
typedef __attribute__((ext_vector_type(4))) float floatx4;  // MFMA C/D

#define HD 768
#define ID 1536
#define NE 8
#define TT 2048
#define SLOTS 5120   // 4096 assignments + per-expert pad to 128

__device__ __forceinline__ float b2f(u16 u) {
    union { unsigned int i; float f; } v; v.i = ((unsigned int)u) << 16; return v.f;
}
__device__ __forceinline__ u16 f2b(float f) {
    union { float f; unsigned int i; } v; v.f = f;
    unsigned int i = v.i;
    return (u16)((i + 0x7FFFu + ((i >> 16) & 1u)) >> 16);  // RNE
}
// async global->LDS, 16B/lane; LDS dest = wave-uniform base + lane*16
__device__ __forceinline__ void glds16(const u16* g, u16* l) {
    __builtin_amdgcn_global_load_lds(
        (const __attribute__((address_space(1))) unsigned int*)g,
        (__attribute__((address_space(3))) unsigned int*)l, 16, 0, 0);
}
// per-block dtype sniff from x's first 256 words (bf16 ~255/256 plausible
// exponents, fp32-reinterpreted ~136/256). sm = 1-int LDS scratch.
__device__ __forceinline__ int sniff_bf(const u16* x16, int* sm, int tid) {
    if (tid < 64) {
        int c = 0;
#pragma unroll
        for (int j = 0; j < 4; ++j) {
            u16 w = x16[tid + 64 * j];
            int ex = (w >> 7) & 0xFF;
            c += (ex >= 118 && ex <= 135);
        }
#pragma unroll
        for (int off = 32; off > 0; off >>= 1) c += __shfl_xor(c, off);
        if (tid == 0) *sm = (c >= 200) ? 1 : 0;
    }
    __syncthreads();
    int bf = *sm;
    __syncthreads();
    return bf;
}

// ---- setup: slot init (blocks 0..19) + router (blocks 0..511) + wpack (all) ----
__global__ void setup_k(const void* __restrict__ x, const void* __restrict__ rw,
                        const void* __restrict__ wg, const void* __restrict__ wu,
                        const void* __restrict__ wd,
                        int* __restrict__ tokof, float* __restrict__ pslot,
                        int* __restrict__ topki, float* __restrict__ topkp,
                        float* __restrict__ blockpart,
                        u16* __restrict__ wgp, u16* __restrict__ wup,
                        u16* __restrict__ wdp) {
    __shared__ u16 smem[8192 + 64];  // wpack tile + router partials/sniff
    const int bid = blockIdx.x, tid = threadIdx.x;
    const int lane = tid & 63, wave = tid >> 6;
    int bf = sniff_bf((const u16*)x, (int*)(smem + 8192), tid);

    {   // slot init
        int i = bid * 256 + tid;
        if (i < SLOTS) { tokof[i] = -1; pslot[i] = 0.f; }
    }

    if (bid < 512) {  // router: one wave per token
        float* sp = (float*)(smem + 8192);  // [4][8]
        int t = bid * 4 + wave;
        const float* xf = (const float*)x + (size_t)t * HD;
        const u16*   xh = (const u16*)x + (size_t)t * HD;
        const float* rf = (const float*)rw;
        const u16*   rh = (const u16*)rw;
        float acc[NE];
#pragma unroll
        for (int e = 0; e < NE; ++e) acc[e] = 0.f;
        for (int j = 0; j < HD / 64; ++j) {
            int h = lane + 64 * j;
            float xv = bf ? b2f(xh[h]) : xf[h];
#pragma unroll
            for (int e = 0; e < NE; ++e)
                acc[e] += xv * (bf ? b2f(rh[h * NE + e]) : rf[h * NE + e]);
        }
#pragma unroll
        for (int e = 0; e < NE; ++e) {
            float v = acc[e];
#pragma unroll
            for (int off = 32; off > 0; off >>= 1) v += __shfl_xor(v, off);
            acc[e] = v;
        }
        if (lane == 0) {
            float m = acc[0];
            for (int e = 1; e < NE; ++e) m = fmaxf(m, acc[e]);
            float p[NE], s = 0.f;
            for (int e = 0; e < NE; ++e) { p[e] = expf(acc[e] - m); s += p[e]; }
            float inv = 1.f / s;
            for (int e = 0; e < NE; ++e) { p[e] *= inv; sp[wave * NE + e] = p[e]; }
            int i1 = 0; float p1 = p[0];
            for (int e = 1; e < NE; ++e) if (p[e] > p1) { p1 = p[e]; i1 = e; }  // first-max
            int i2 = -1; float p2 = -1.f;
            for (int e = 0; e < NE; ++e) if (e != i1 && p[e] > p2) { p2 = p[e]; i2 = e; }
            if (i2 < 0) { i2 = (i1 + 1) & 7; p2 = p[i2]; }  // NaN guard
            float sn = 1.f / (p1 + p2);
            topki[2 * t] = i1;  topki[2 * t + 1] = i2;
            topkp[2 * t] = p1 * sn;  topkp[2 * t + 1] = p2 * sn;
        }
        __syncthreads();
        if (tid < NE)
            blockpart[bid * NE + tid] =
                sp[tid] + sp[NE + tid] + sp[2 * NE + tid] + sp[3 * NE + tid];
        __syncthreads();
    }

    {   // wpack: one 64k x 128n sub-tile per block (3456 tasks)
        const void* src; u16* dst; int K, N, ktiles, ntiles, e, kt, nt;
        if (bid < 2304) {
            int z = bid / 144, rem = bid - z * 144;
            nt = rem / 12; kt = rem - nt * 12;
            e = z & 7;
            src = (z < NE) ? wg : wu;
            dst = (z < NE) ? wgp : wup;
            K = HD; N = ID; ktiles = 12; ntiles = 12;
        } else {
            int T2 = bid - 2304;
            e = T2 / 144; int rem = T2 - e * 144;
            nt = rem / 24; kt = rem - nt * 24;
            src = wd; dst = wdp; K = ID; N = HD; ktiles = 24; ntiles = 6;
        }
        int kr = tid >> 2, ng = (tid & 3) * 32;
        size_t srow = ((size_t)e * K + (size_t)kt * 64 + kr) * N + (size_t)nt * 128 + ng;
        union { uint4 v[4]; u16 u[32]; } buf;
        if (bf) {
            const u16* s = (const u16*)src + srow;
#pragma unroll
            for (int c = 0; c < 4; ++c) buf.v[c] = *(const uint4*)&s[c * 8];
        } else {
            const float* s = (const float*)src + srow;
#pragma unroll
            for (int c = 0; c < 8; ++c) {
                float4 f = *(const float4*)&s[c * 4];
                buf.u[c * 4 + 0] = f2b(f.x); buf.u[c * 4 + 1] = f2b(f.y);
                buf.u[c * 4 + 2] = f2b(f.z); buf.u[c * 4 + 3] = f2b(f.w);
            }
        }
#pragma unroll
        for (int jj = 0; jj < 32; ++jj) {
            int n = ng + jj;
            smem[n * 64 + (((kr >> 3) ^ (n & 7)) << 3) + (kr & 7)] = buf.u[jj];
        }
        __syncthreads();
        u16* d = dst + ((((size_t)e * ntiles + nt) * ktiles + kt) << 13);
#pragma unroll
        for (int i = 0; i < 4; ++i) {
            int off = tid * 8 + i * 2048;
            *(uint4*)(d + off) = *(const uint4*)&smem[off];
        }
    }
}

// ---- sortscat: 8 blocks; redundant histogram -> bases; atomic-free ranks ----
__global__ void sortscat_k(const void* __restrict__ x,
                           const int* __restrict__ topki, const float* __restrict__ topkp,
                           const float* __restrict__ blockpart,
                           int* __restrict__ base, int* __restrict__ total,
                           int* __restrict__ tokof, float* __restrict__ pslot,
                           int* __restrict__ slotmap, void* __restrict__ out) {
    __shared__ int tk[TT * 2];
    __shared__ int histAll[NE], histPre[NE], lbase[NE], lcnt[NE];
    __shared__ float psum[NE];
    __shared__ int sm1;
    const int bid = blockIdx.x, tid = threadIdx.x;
    int bf = sniff_bf((const u16*)x, &sm1, tid);
    if (tid < NE) { histAll[tid] = 0; histPre[tid] = 0; lcnt[tid] = 0; psum[tid] = 0.f; }
    __syncthreads();
    int pre_end = 2 * bid * 256;
    for (int i = tid; i < TT * 2; i += 256) {
        int e = topki[i] & 7;
        tk[i] = e;
        atomicAdd(&histAll[e], 1);
        if (i < pre_end) atomicAdd(&histPre[e], 1);
    }
    if (bid == 0)
        for (int i = tid; i < 512 * NE; i += 256) atomicAdd(&psum[i & 7], blockpart[i]);
    __syncthreads();
    if (tid == 0) {
        int cum = 0; float aux = 0.f;
        for (int e = 0; e < NE; ++e) {
            lbase[e] = cum;
            cum += (histAll[e] + 127) & ~127;
            aux += ((float)histAll[e] / (float)(TT * 2)) * (psum[e] / (float)TT);
        }
        if (bid == 0) {
            for (int e = 0; e < NE; ++e) base[e] = lbase[e];
            *total = cum;
            float auxv = aux * (float)NE * 0.01f;
            if (bf) ((u16*)out)[(size_t)TT * HD] = f2b(auxv);
            else    ((float*)out)[(size_t)TT * HD] = auxv;
        }
    }
    __syncthreads();
    int t = bid * 256 + tid;
    int e0 = tk[2 * t], e1 = tk[2 * t + 1];
    float q0 = topkp[2 * t], q1 = topkp[2 * t + 1];
    int l0 = atomicAdd(&lcnt[e0], 1);
    int l1 = atomicAdd(&lcnt[e1], 1);
    int s0 = min(max(lbase[e0] + histPre[e0] + l0, 0), SLOTS - 1);
    int s1 = min(max(lbase[e1] + histPre[e1] + l1, 0), SLOTS - 1);
    tokof[s0] = t;  pslot[s0] = q0;  slotmap[2 * t] = s0;
    tokof[s1] = t;  pslot[s1] = q1;  slotmap[2 * t + 1] = s1;
}

// ---- apack: gather token rows -> packed swizzled A tiles [mt][kt][16KB] ----
__global__ void apack_k(const void* __restrict__ x,
                        const int* __restrict__ tokof, const int* __restrict__ total,
                        u16* __restrict__ apack) {
    __shared__ int sm1;
    int tid = threadIdx.x;
    int bf = sniff_bf((const u16*)x, &sm1, tid);
    int mt = blockIdx.y, kt = blockIdx.x;
    if (mt * 128 >= *total) return;
    int ml = tid >> 1, half = tid & 1;  // row in tile, 32-k half
    int tok = tokof[mt * 128 + ml];
    union { uint4 v[4]; u16 u[32]; } buf;
    if ((unsigned)tok < (unsigned)TT) {
        if (bf) {
            const u16* s = (const u16*)x + (size_t)tok * HD + kt * 64 + half * 32;
#pragma unroll
            for (int c = 0; c < 4; ++c) buf.v[c] = *(const uint4*)&s[c * 8];
        } else {
            const float* s = (const float*)x + (size_t)tok * HD + kt * 64 + half * 32;
#pragma unroll
            for (int c = 0; c < 8; ++c) {
                float4 f = *(const float4*)&s[c * 4];
                buf.u[c * 4 + 0] = f2b(f.x); buf.u[c * 4 + 1] = f2b(f.y);
                buf.u[c * 4 + 2] = f2b(f.z); buf.u[c * 4 + 3] = f2b(f.w);
            }
        }
    } else {
#pragma unroll
        for (int c = 0; c < 4; ++c) buf.v[c] = make_uint4(0, 0, 0, 0);
    }
    u16* dst = apack + (((size_t)mt * 12 + kt) << 13) + ml * 64;
#pragma unroll
    for (int c = 0; c < 4; ++c) {
        int pc = (half * 4 + c) ^ (ml & 7);  // swizzled chunk
        *(uint4*)(dst + pc * 8) = buf.v[c];
    }
}

// ---- GEMM1: act = silu(A Wg) * (A Wu); 128x128 block, 64x64/wave ----
__global__ __launch_bounds__(256, 2) void gemm1_k(
        const u16* __restrict__ apack, const u16* __restrict__ wgp,
        const u16* __restrict__ wup, const int* __restrict__ base,
        const int* __restrict__ total, u16* __restrict__ actp) {
    __shared__ u16 smem[24576];  // As 8192 u16 | Bg 8192 | Bu 8192
    u16* As = smem; u16* Bg = smem + 8192; u16* Bu = smem + 16384;
    int mt = blockIdx.y;
    if (mt * 128 >= *total) return;
    int e = 7;
    while (e > 0 && mt * 128 < base[e]) --e;
    int nt = blockIdx.x;
    int tid = threadIdx.x, lane = tid & 63, wave = tid >> 6;
    int wm = (wave & 1) * 64, wn = (wave >> 1) * 64;
    int llo = lane & 15, lq = lane >> 4;
    const u16* atile = apack + (((size_t)mt * 12) << 13);
    const u16* gtile = wgp + ((((size_t)e * 12 + nt) * 12) << 13);
    const u16* utile = wup + ((((size_t)e * 12 + nt) * 12) << 13);
    floatx4 accG[4][4], accU[4][4];
#pragma unroll
    for (int i = 0; i < 4; ++i)
#pragma unroll
        for (int j = 0; j < 4; ++j) {
            accG[i][j] = floatx4{0.f, 0.f, 0.f, 0.f};
            accU[i][j] = floatx4{0.f, 0.f, 0.f, 0.f};
        }
    for (int kt = 0; kt < 12; ++kt) {
        const u16* ga = atile + (kt << 13);
        const u16* gg = gtile + (kt << 13);
        const u16* gu = utile + (kt << 13);
        __syncthreads();
#pragma unroll
        for (int i = 0; i < 4; ++i) {
            int off = tid * 8 + i * 2048;
            glds16(ga + off, As + off);
            glds16(gg + off, Bg + off);
            glds16(gu + off, Bu + off);
        }
        asm volatile("s_waitcnt vmcnt(0)" ::: "memory");
        __syncthreads();
#pragma unroll
        for (int kk = 0; kk < 2; ++kk) {
            int q = kk * 4 + lq;
            bhalf8 af[4], bg[4], bu[4];
#pragma unroll
            for (int i = 0; i < 4; ++i) {
                int m = wm + i * 16 + llo;
                af[i] = *(const bhalf8*)&As[m * 64 + ((q ^ (m & 7)) << 3)];
                int n = wn + i * 16 + llo;
                bg[i] = *(const bhalf8*)&Bg[n * 64 + ((q ^ (n & 7)) << 3)];
                bu[i] = *(const bhalf8*)&Bu[n * 64 + ((q ^ (n & 7)) << 3)];
            }
#pragma unroll
            for (int i = 0; i < 4; ++i)
#pragma unroll
                for (int j = 0; j < 4; ++j) {
                    accG[i][j] = __builtin_amdgcn_mfma_f32_16x16x32_bf16(af[i], bg[j], accG[i][j], 0, 0, 0);
                    accU[i][j] = __builtin_amdgcn_mfma_f32_16x16x32_bf16(af[i], bu[j], accU[i][j], 0, 0, 0);
                }
        }
    }
    __syncthreads();
    u16* Ah = smem;  // 32 KB
    int q4 = lq * 4;
#pragma unroll
    for (int i = 0; i < 4; ++i)
#pragma unroll
        for (int j = 0; j < 4; ++j)
#pragma unroll
            for (int rr = 0; rr < 4; ++rr) {
                int m = wm + i * 16 + q4 + rr;
                int n = wn + j * 16 + llo;
                float g = accG[i][j][rr], u = accU[i][j][rr];
                Ah[m * 128 + n] = f2b((g / (1.f + expf(-g))) * u);
            }
    __syncthreads();
    u16* dst = actp + (((size_t)mt * 24 + nt * 2) << 13);
#pragma unroll
    for (int s = 0; s < 2; ++s)
#pragma unroll
        for (int i = 0; i < 4; ++i) {
            int off = tid * 8 + i * 2048;
            int m = off >> 6;
            int pc = (off >> 3) & 7;
            int q = pc ^ (m & 7);
            *(uint4*)(dst + ((size_t)s << 13) + off) =
                *(const uint4*)&Ah[m * 128 + s * 64 + q * 8];
        }
}

// ---- GEMM2: y = pslot * (act Wd); 128x128 block, 64x64/wave ----
__global__ __launch_bounds__(256, 2) void gemm2_k(
        const u16* __restrict__ actp, const u16* __restrict__ wdp,
        const int* __restrict__ base, const int* __restrict__ total,
        const float* __restrict__ pslot, float* __restrict__ y) {
    __shared__ u16 smem[16384];  // As 8192 | Bs 8192
    u16* As = smem; u16* Bs = smem + 8192;
    int mt = blockIdx.y;
    if (mt * 128 >= *total) return;
    int e = 7;
    while (e > 0 && mt * 128 < base[e]) --e;
    int nt = blockIdx.x;  // 0..5
    int tid = threadIdx.x, lane = tid & 63, wave = tid >> 6;
    int wm = (wave & 1) * 64, wn = (wave >> 1) * 64;
    int llo = lane & 15, lq = lane >> 4;
    const u16* atile = actp + (((size_t)mt * 24) << 13);
    const u16* btile = wdp + ((((size_t)e * 6 + nt) * 24) << 13);
    floatx4 acc[4][4];
#pragma unroll
    for (int i = 0; i < 4; ++i)
#pragma unroll
        for (int j = 0; j < 4; ++j) acc[i][j] = floatx4{0.f, 0.f, 0.f, 0.f};
    for (int kt = 0; kt < 24; ++kt) {
        const u16* ga = atile + (kt << 13);
        const u16* gb = btile + (kt << 13);
        __syncthreads();
#pragma unroll
        for (int i = 0; i < 4; ++i) {
            int off = tid * 8 + i * 2048;
            glds16(ga + off, As + off);
            glds16(gb + off, Bs + off);
        }
        asm volatile("s_waitcnt vmcnt(0)" ::: "memory");
        __syncthreads();
#pragma unroll
        for (int kk = 0; kk < 2; ++kk) {
            int q = kk * 4 + lq;
            bhalf8 af[4], bfr[4];
#pragma unroll
            for (int i = 0; i < 4; ++i) {
                int m = wm + i * 16 + llo;
                af[i] = *(const bhalf8*)&As[m * 64 + ((q ^ (m & 7)) << 3)];
                int n = wn + i * 16 + llo;
                bfr[i] = *(const bhalf8*)&Bs[n * 64 + ((q ^ (n & 7)) << 3)];
            }
#pragma unroll
            for (int i = 0; i < 4; ++i)
#pragma unroll
                for (int j = 0; j < 4; ++j)
                    acc[i][j] = __builtin_amdgcn_mfma_f32_16x16x32_bf16(af[i], bfr[j], acc[i][j], 0, 0, 0);
        }
    }
    int q4 = lq * 4;
#pragma unroll
    for (int i = 0; i < 4; ++i)
#pragma unroll
        for (int rr = 0; rr < 4; ++rr) {
            int m = mt * 128 + wm + i * 16 + q4 + rr;
            float p = pslot[m];  // 0 for padded rows
#pragma unroll
            for (int j = 0; j < 4; ++j) {
                int n = nt * 128 + wn + j * 16 + llo;
                y[(size_t)m * HD + n] = p * acc[i][j][rr];
            }
        }
}

// ---- combine two expert slots per token ----
__global__ void combine_k(const void* __restrict__ x, const float* __restrict__ y,
                          const int* __restrict__ slotmap, void* __restrict__ out) {
    __shared__ int sm1;
    int tid = threadIdx.x;
    int bf = sniff_bf((const u16*)x, &sm1, tid);
    int g = blockIdx.x * 256 + tid;  // TT*192 quads
    int t = g / 192;
    int q = (g - t * 192) * 4;
    int s0 = min(max(slotmap[2 * t], 0), SLOTS - 1);
    int s1 = min(max(slotmap[2 * t + 1], 0), SLOTS - 1);
    float4 a = *(const float4*)&y[(size_t)s0 * HD + q];
    float4 b = *(const float4*)&y[(size_t)s1 * HD + q];
    float4 rv;
    rv.x = a.x + b.x; rv.y = a.y + b.y; rv.z = a.z + b.z; rv.w = a.w + b.w;
    if (bf) {
        ushort4 o;
        o.x = f2b(rv.x); o.y = f2b(rv.y); o.z = f2b(rv.z); o.w = f2b(rv.w);
        *(ushort4*)((u16*)out + (size_t)t * HD + q) = o;
    } else {
        *(float4*)((float*)out + (size_t)t * HD + q) = rv;
    }
}

extern "C" void kernel_launch(void* const* d_in, const int* in_sizes, int n_in,
                              void* d_out, int out_size, void* d_ws, size_t ws_size,
                              hipStream_t stream) {
    if (ws_size < 80322816u) return;  // clean absmax-fail beats a wild write
    const void* x  = d_in[0];
    const void* rw = d_in[1];
    const void* wg = d_in[2];
    const void* wu = d_in[3];
    const void* wd = d_in[4];
    char* ws = (char*)d_ws;

    // workspace layout (bytes), total 80,322,816
    int*   basep   = (int*)(ws + 64);
    int*   totalp  = (int*)(ws + 96);
    int*   topki   = (int*)(ws + 256);         // [4096]
    float* topkp   = (float*)(ws + 16640);     // [4096]
    int*   tokof   = (int*)(ws + 33024);       // [5120]
    float* pslotp  = (float*)(ws + 53504);     // [5120]
    int*   slotmap = (int*)(ws + 73984);       // [4096]
    float* blockpart = (float*)(ws + 90368);   // [512*8]
    u16*   apack   = (u16*)(ws + 106752);      // 40*12 tiles * 16 KB
    u16*   actp    = (u16*)(ws + 7971072);     // 40*24 tiles
    u16*   wgp     = (u16*)(ws + 23699712);    // 8*12*12 tiles
    u16*   wup     = (u16*)(ws + 42574080);
    u16*   wdp     = (u16*)(ws + 61448448);    // 8*6*24 tiles -> 80,322,816
    float* ybuf    = (float*)(ws + 23699712);  // overlays wgp: stream-ordered safe

    setup_k<<<3456, 256, 0, stream>>>(x, rw, wg, wu, wd, tokof, pslotp,
                                      topki, topkp, blockpart, wgp, wup, wdp);
    sortscat_k<<<8, 256, 0, stream>>>(x, topki, topkp, blockpart, basep, totalp,
                                      tokof, pslotp, slotmap, d_out);
    apack_k<<<dim3(12, 40), 256, 0, stream>>>(x, tokof, totalp, apack);
    gemm1_k<<<dim3(12, 40), 256, 0, stream>>>(apack, wgp, wup, basep, totalp, actp);
    gemm2_k<<<dim3(6, 40), 256, 0, stream>>>(actp, wdp, basep, totalp, pslotp, ybuf);
    combine_k<<<1536, 256, 0, stream>>>(x, ybuf, slotmap, d_out);
}